// Round 17
// baseline (597.339 us; speedup 1.0000x reference)
//
#include <hip/hip_runtime.h>
#include <math.h>

#define NEDGE 600000
#define NUSER 50000
#define NITEM 50000
#define DIMT  128
#define NIN   25000
#define NTVAL 1000

typedef unsigned short ushort_t;
typedef __attribute__((ext_vector_type(8))) short bf16x8;
typedef __attribute__((ext_vector_type(8))) unsigned short us8;
typedef __attribute__((ext_vector_type(4))) float f32x4;
typedef __attribute__((ext_vector_type(4))) unsigned upk4;

// packed element: low16 = hi bf16, high16 = lo bf16 ; value = fh + fl
__device__ __forceinline__ unsigned pack_hl(float f) {
    unsigned u = __float_as_uint(f);
    unsigned r = u + 0x7fffu + ((u >> 16) & 1u);
    unsigned h = (r >> 16) & 0xffffu;
    float fh = __uint_as_float(h << 16);
    float fl = f - fh;
    unsigned ul = __float_as_uint(fl);
    unsigned rl = ul + 0x7fffu + ((ul >> 16) & 1u);
    return h | (rl & 0xffff0000u);
}
__device__ __forceinline__ void split_bf16(float f, ushort_t& h, ushort_t& l) {
    unsigned p = pack_hl(f);
    h = (ushort_t)(p & 0xffffu);
    l = (ushort_t)(p >> 16);
}

// deinterleave 8 packed uints -> bf16x8 hi, bf16x8 lo
__device__ __forceinline__ void unpack_frag(upk4 p0, upk4 p1, bf16x8& ah, bf16x8& al) {
    upk4 h, l;
#if __has_builtin(__builtin_amdgcn_perm)
    h.x = __builtin_amdgcn_perm(p0.y, p0.x, 0x05040100u);
    h.y = __builtin_amdgcn_perm(p0.w, p0.z, 0x05040100u);
    h.z = __builtin_amdgcn_perm(p1.y, p1.x, 0x05040100u);
    h.w = __builtin_amdgcn_perm(p1.w, p1.z, 0x05040100u);
    l.x = __builtin_amdgcn_perm(p0.y, p0.x, 0x07060302u);
    l.y = __builtin_amdgcn_perm(p0.w, p0.z, 0x07060302u);
    l.z = __builtin_amdgcn_perm(p1.y, p1.x, 0x07060302u);
    l.w = __builtin_amdgcn_perm(p1.w, p1.z, 0x07060302u);
#else
    h.x = (p0.x & 0xffffu) | (p0.y << 16);
    h.y = (p0.z & 0xffffu) | (p0.w << 16);
    h.z = (p1.x & 0xffffu) | (p1.y << 16);
    h.w = (p1.z & 0xffffu) | (p1.w << 16);
    l.x = (p0.x >> 16) | (p0.y & 0xffff0000u);
    l.y = (p0.z >> 16) | (p0.w & 0xffff0000u);
    l.z = (p1.x >> 16) | (p1.y & 0xffff0000u);
    l.w = (p1.z >> 16) | (p1.w & 0xffff0000u);
#endif
    ah = __builtin_bit_cast(bf16x8, h);
    al = __builtin_bit_cast(bf16x8, l);
}

// slice-major plane addressing: elem (row,k) at ((k>>4)*nr + row)*16 + (k&15)
__device__ __forceinline__ size_t sm_addr(int row, int k, int nr) {
    return ((size_t)(k >> 4) * (unsigned)nr + (unsigned)row) * 16 + (k & 15);
}

// ---------------------------------------------------------------------------
// prep: LUT (4-way ILP) | weight cvt (write-contiguous) | x cvt + edge pack |
//       XCD-partitioned histogram
// ---------------------------------------------------------------------------
struct WDesc { const float* src; int K; int N; unsigned dst; };
struct WDescs { WDesc d[16]; };

#define PREP_LUT  500
#define PREP_CVTW 256
#define PREP_CVTX 512
#define HIST_CH   256
#define PREP_HIST (8 * HIST_CH)
#define DRANGE    (NUSER / 8)

__global__ __launch_bounds__(256) void prep_kernel(
        WDescs wd, ushort_t* __restrict__ WT,
        const float* __restrict__ teW1, const float* __restrict__ teb1,
        const float* __restrict__ teW2, const float* __restrict__ teb2,
        float* __restrict__ Tlut,
        const float* __restrict__ xu, const float* __restrict__ xi,
        unsigned* __restrict__ xup, unsigned* __restrict__ xip,
        const int* __restrict__ s0, const int* __restrict__ d0,
        const int* __restrict__ s1, const int* __restrict__ d1,
        unsigned* __restrict__ pe0, unsigned* __restrict__ pe1,
        int* __restrict__ cnt2) {
    __shared__ float sE[2][128];
    __shared__ float sH[2][128];
    int b = blockIdx.x;
    int tid = threadIdx.x;
    if (b < PREP_LUT) {
        int r = tid >> 7, j = tid & 127;
        int t = b * 2 + r;
        {
            int jj = j & 63;
            const float Lf = 9.210340371976184f;
            float p  = -Lf * (float)jj;
            float ae = p * 0.015625f;
            float freq = (float)exp((double)ae);
            float arg  = (float)t * freq;
            double a = (double)arg;
            sE[r][j] = (j < 64) ? (float)cos(a) : (float)sin(a);
        }
        __syncthreads();
        {
            float a0 = 0.f, a1 = 0.f, a2 = 0.f, a3 = 0.f;
            for (int k = 0; k < 128; k += 4) {
                a0 = fmaf(sE[r][k],     teW1[(k)     * 128 + j], a0);
                a1 = fmaf(sE[r][k + 1], teW1[(k + 1) * 128 + j], a1);
                a2 = fmaf(sE[r][k + 2], teW1[(k + 2) * 128 + j], a2);
                a3 = fmaf(sE[r][k + 3], teW1[(k + 3) * 128 + j], a3);
            }
            float acc = teb1[j] + ((a0 + a1) + (a2 + a3));
            float s = 1.f / (1.f + expf(-acc));
            sH[r][j] = acc * s;
        }
        __syncthreads();
        {
            float a0 = 0.f, a1 = 0.f, a2 = 0.f, a3 = 0.f;
            for (int k = 0; k < 128; k += 4) {
                a0 = fmaf(sH[r][k],     teW2[(k)     * 128 + j], a0);
                a1 = fmaf(sH[r][k + 1], teW2[(k + 1) * 128 + j], a1);
                a2 = fmaf(sH[r][k + 2], teW2[(k + 2) * 128 + j], a2);
                a3 = fmaf(sH[r][k + 3], teW2[(k + 3) * 128 + j], a3);
            }
            Tlut[(size_t)t * 128 + j] = teb2[j] + ((a0 + a1) + (a2 + a3));
        }
    } else if (b < PREP_LUT + PREP_CVTW) {
        int g = (b - PREP_LUT) * 256 + tid;
        int gs = PREP_CVTW * 256;
#pragma unroll 1
        for (int i = 0; i < 16; ++i) {
            const WDesc w = wd.d[i];
            int sz = w.K * w.N;
            int ng = sz >> 3;
            int kshift = 31 - __clz(w.K);
            int kmask = w.K - 1;
            ushort_t* ph = WT + w.dst;
            ushort_t* pl = ph + sz;
            for (int t = g; t < ng; t += gs) {
                int e8 = t << 3;
                int n  = e8 >> kshift;
                int k0 = e8 & kmask;
                us8 hb, lb;
#pragma unroll
                for (int j = 0; j < 8; ++j) {
                    ushort_t h, l;
                    split_bf16(w.src[(size_t)(k0 + j) * w.N + n], h, l);
                    hb[j] = h; lb[j] = l;
                }
                *reinterpret_cast<us8*>(ph + e8) = hb;
                *reinterpret_cast<us8*>(pl + e8) = lb;
            }
        }
    } else if (b < PREP_LUT + PREP_CVTW + PREP_CVTX) {
        int g = (b - PREP_LUT - PREP_CVTW) * 256 + tid;
        int gs = PREP_CVTX * 256;
        for (int i = g; i < NUSER * 64; i += gs) {
            int row = i >> 6, k = i & 63;
            xup[sm_addr(row, k, NUSER)] = pack_hl(xu[i]);
        }
        for (int i = g; i < NITEM * 32; i += gs) {
            int row = i >> 5, k = i & 31;
            xip[sm_addr(row, k, NITEM)] = pack_hl(xi[i]);
        }
        for (int i = g; i < NEDGE; i += gs) {
            pe0[i] = ((unsigned)d0[i] & 0xffffu) | ((unsigned)s0[i] << 16);
            pe1[i] = ((unsigned)d1[i] & 0xffffu) | ((unsigned)s1[i] << 16);
        }
    } else {
        int hb = b - PREP_LUT - PREP_CVTW - PREP_CVTX;
        int r = hb & 7, c = hb >> 3;
        int lo = r * DRANGE, hi = lo + DRANGE;
        const int epb = (NEDGE + HIST_CH - 1) / HIST_CH;
        int e0 = c * epb, e1 = min(e0 + epb, NEDGE);
        for (int e = e0 + tid; e < e1; e += 256) {
            int d = d0[e];
            if (d >= lo && d < hi) atomicAdd(&cnt2[d], 1);
        }
        for (int e = e0 + tid; e < e1; e += 256) {
            int d = d1[e];
            if (d >= lo && d < hi) atomicAdd(&cnt2[NUSER + d], 1);
        }
    }
}

// ---------------------------------------------------------------------------
// MFMA GEMM (split-bf16, 3-pass):  Y = act( A@W1 [+ A2@W2] + bias [+ res] )
// A: packed uint planes, SLICE-MAJOR (stride anr). W: transposed hi/lo.
// OUTMODE bit0: fp32 row-major Yf; bit1: slice-major packed Yp (stride ynr).
// ---------------------------------------------------------------------------
#define ACT_NONE 0
#define ACT_RELU 1

struct MProb {
    const unsigned *A1p; int K1;
    const unsigned *A2p; int K2;
    const ushort_t *W1, *W2;            // hi plane; lo at +NOUT*K
    const float* bias; const float* res; const int* tidx;
    float* Yf; unsigned* Yp;
    int M; int nblk; int anr; int ynr;
};

template<int NOUT, int ACT, bool DUAL, int RESMODE, int OUTMODE>
__global__ __launch_bounds__(256)
void mgemm_kernel(MProb q0, MProb q1) {
    constexpr int WN  = (NOUT >= 64) ? 64 : NOUT;
    constexpr int NWC = NOUT / WN;
    constexpr int NWR = 4 / NWC;
    constexpr int BM  = NWR * 64;
    constexpr int NF  = WN / 16;

    const bool firstp = (blockIdx.x < (unsigned)q0.nblk);
    const MProb& q = firstp ? q0 : q1;
    const int bid = firstp ? blockIdx.x : (blockIdx.x - q0.nblk);

    const int w    = threadIdx.x >> 6;
    const int lane = threadIdx.x & 63;
    const int wc   = w % NWC;
    const int wr   = w / NWC;
    const int mw   = bid * BM + wr * 64;
    const int nw   = wc * WN;
    const int lr   = lane & 15;
    const int lkg  = lane >> 4;

    f32x4 acc[4][NF];
#pragma unroll
    for (int i = 0; i < 4; ++i)
#pragma unroll
        for (int j = 0; j < NF; ++j) acc[i][j] = (f32x4)0.f;

    const int nkt1 = q.K1 / 32;
    const int nkt  = nkt1 + (DUAL ? q.K2 / 32 : 0);

    upk4 pa[4][2];
    auto loadA = [&](int kt) {
        const unsigned* Ap; int kk;
        if (!DUAL || kt < nkt1) { Ap = q.A1p; kk = kt * 32; }
        else                    { Ap = q.A2p; kk = (kt - nkt1) * 32; }
        const int kb = kk + lkg * 8;          // kb % 16 in {0,8}
#pragma unroll
        for (int mf = 0; mf < 4; ++mf) {
            int row = mw + mf * 16 + lr;
            if (row < q.M) {
                const upk4* p = reinterpret_cast<const upk4*>(Ap + sm_addr(row, kb, q.anr));
                pa[mf][0] = p[0]; pa[mf][1] = p[1];
            } else {
                pa[mf][0] = (upk4)0u; pa[mf][1] = (upk4)0u;
            }
        }
    };

    loadA(0);
#pragma unroll 1
    for (int kt = 0; kt < nkt; ++kt) {
        bf16x8 a_h[4], a_l[4];
#pragma unroll
        for (int mf = 0; mf < 4; ++mf) unpack_frag(pa[mf][0], pa[mf][1], a_h[mf], a_l[mf]);
        if (kt + 1 < nkt) loadA(kt + 1);          // prefetch next A tile

        const ushort_t* Wh; int K, kk;
        if (!DUAL || kt < nkt1) { Wh = q.W1; K = q.K1; kk = kt * 32; }
        else                    { Wh = q.W2; K = q.K2; kk = (kt - nkt1) * 32; }
        const ushort_t* Wl = Wh + (size_t)NOUT * K;
        const int kb = kk + lkg * 8;
        bf16x8 b_h[NF], b_l[NF];
#pragma unroll
        for (int nf = 0; nf < NF; ++nf) {
            int col = nw + nf * 16 + lr;
            b_h[nf] = *reinterpret_cast<const bf16x8*>(Wh + (size_t)col * K + kb);
            b_l[nf] = *reinterpret_cast<const bf16x8*>(Wl + (size_t)col * K + kb);
        }
#pragma unroll
        for (int mf = 0; mf < 4; ++mf)
#pragma unroll
            for (int nf = 0; nf < NF; ++nf) {
                acc[mf][nf] = __builtin_amdgcn_mfma_f32_16x16x32_bf16(a_h[mf], b_h[nf], acc[mf][nf], 0, 0, 0);
                acc[mf][nf] = __builtin_amdgcn_mfma_f32_16x16x32_bf16(a_h[mf], b_l[nf], acc[mf][nf], 0, 0, 0);
                acc[mf][nf] = __builtin_amdgcn_mfma_f32_16x16x32_bf16(a_l[mf], b_h[nf], acc[mf][nf], 0, 0, 0);
            }
    }

    // all reads complete before in-place epilogue stores (waves share rows)
    __syncthreads();

    float bcol[NF];
#pragma unroll
    for (int nf = 0; nf < NF; ++nf) bcol[nf] = q.bias[nw + nf * 16 + lr];

#pragma unroll
    for (int mf = 0; mf < 4; ++mf) {
#pragma unroll
        for (int r = 0; r < 4; ++r) {
            int row = mw + mf * 16 + lkg * 4 + r;
            if (row >= q.M) continue;
            const float* rp = nullptr;
            if (RESMODE == 2) { int tv = q.tidx[row]; rp = q.res + (size_t)tv * NOUT; }
#pragma unroll
            for (int nf = 0; nf < NF; ++nf) {
                int col = nw + nf * 16 + lr;
                float v = acc[mf][nf][r] + bcol[nf];
                if (RESMODE == 2) v += rp[col];
                if (ACT == ACT_RELU) v = fmaxf(v, 0.f);
                if (OUTMODE & 1) q.Yf[(size_t)row * NOUT + col] = v;
                if (OUTMODE & 2) q.Yp[sm_addr(row, col, q.ynr)] = pack_hl(v);
            }
        }
    }
}

// ---------------------------------------------------------------------------
// CSR scans (verified R14 versions)
// ---------------------------------------------------------------------------
#define SCAN_CHUNK 2048
#define GSCAN 25

__global__ __launch_bounds__(256) void scan1x2_kernel(const int* __restrict__ cnt2,
                                                      int* __restrict__ bsum2) {
    __shared__ int sdata[256];
    int p = blockIdx.x / GSCAN, b = blockIdx.x % GSCAN;
    const int* cnt = cnt2 + p * NUSER;
    int base = b * SCAN_CHUNK + threadIdx.x * 8;
    int s = 0;
#pragma unroll
    for (int j = 0; j < 8; ++j) { int i = base + j; if (i < NUSER) s += cnt[i]; }
    sdata[threadIdx.x] = s;
    __syncthreads();
    for (int st = 128; st > 0; st >>= 1) {
        if ((int)threadIdx.x < st) sdata[threadIdx.x] += sdata[threadIdx.x + st];
        __syncthreads();
    }
    if (threadIdx.x == 0) bsum2[p * 32 + b] = sdata[0];
}

__global__ __launch_bounds__(256) void scan3x2_kernel(const int* __restrict__ cnt2,
                                                      const int* __restrict__ bsum2,
                                                      int* __restrict__ off_ui,
                                                      int* __restrict__ off_iu,
                                                      int* __restrict__ wp2) {
    __shared__ int sth[256];
    int p = blockIdx.x / GSCAN, b = blockIdx.x % GSCAN;
    const int* cnt = cnt2 + p * NUSER;
    int* offs = p ? off_iu : off_ui;
    int* wp = wp2 + p * NUSER;
    int t = threadIdx.x;
    int boff = 0;
    for (int i = 0; i < b; ++i) boff += bsum2[p * 32 + i];
    int base = b * SCAN_CHUNK + t * 8;
    int loc[8];
    int s = 0;
#pragma unroll
    for (int j = 0; j < 8; ++j) {
        int i = base + j;
        int v = (i < NUSER) ? cnt[i] : 0;
        loc[j] = s; s += v;
    }
    sth[t] = s;
    __syncthreads();
    for (int st = 1; st < 256; st <<= 1) {
        int v = (t >= st) ? sth[t - st] : 0;
        __syncthreads();
        sth[t] += v;
        __syncthreads();
    }
    int exc = (t == 0) ? 0 : sth[t - 1];
#pragma unroll
    for (int j = 0; j < 8; ++j) {
        int i = base + j;
        if (i < NUSER) { int o = boff + exc + loc[j]; offs[i] = o; wp[i] = o; }
    }
    if (b == GSCAN - 1 && t == 255) offs[NUSER] = boff + sth[255];
}

// ---------------------------------------------------------------------------
// XCD-partitioned bucket fill from packed edges (dst|src<<16)
// ---------------------------------------------------------------------------
#define FILL_CH 256

__global__ __launch_bounds__(256) void fill2p_kernel(
        const unsigned* __restrict__ pe0, const unsigned* __restrict__ pe1,
        int* __restrict__ wp2,
        ushort_t* __restrict__ bkt0, ushort_t* __restrict__ bkt1) {
    int r = blockIdx.x & 7, c = blockIdx.x >> 3;
    int lo = r * DRANGE, hi = lo + DRANGE;
    const int epb = (NEDGE + FILL_CH - 1) / FILL_CH;
    int e0 = c * epb, e1 = min(e0 + epb, NEDGE);
#pragma unroll 4
    for (int e = e0 + (int)threadIdx.x; e < e1; e += 256) {
        unsigned p = pe0[e];
        int d = (int)(p & 0xffffu);
        if (d >= lo && d < hi) { int pos = atomicAdd(&wp2[d], 1); bkt0[pos] = (ushort_t)(p >> 16); }
    }
#pragma unroll 4
    for (int e = e0 + (int)threadIdx.x; e < e1; e += 256) {
        unsigned p = pe1[e];
        int d = (int)(p & 0xffffu);
        if (d >= lo && d < hi) { int pos = atomicAdd(&wp2[NUSER + d], 1); bkt1[pos] = (ushort_t)(p >> 16); }
    }
}

// ---------------------------------------------------------------------------
// Slice-partitioned segment-mean, 4-lane groups, 4-edge ILP.
// NON-TEMPORAL output stores + bkt loads: keeps the 3.2MB H slice L2-resident
// (working set was slice 3.2 + Op 3.2 + bkt 0.3 > 4MB L2 -> thrash).
// ---------------------------------------------------------------------------
struct GProb { const unsigned* Hp; const int* offs; const ushort_t* bkt;
               unsigned* Op; int N; };
#define GCH64 782   // ceil(50000/64)

__device__ __forceinline__ void gacc(float4& a, upk4 v) {
    a.x += __uint_as_float(v.x << 16);
    a.y += __uint_as_float(v.y << 16);
    a.z += __uint_as_float(v.z << 16);
    a.w += __uint_as_float(v.w << 16);
    a.x += __uint_as_float(v.x & 0xffff0000u);
    a.y += __uint_as_float(v.y & 0xffff0000u);
    a.z += __uint_as_float(v.z & 0xffff0000u);
    a.w += __uint_as_float(v.w & 0xffff0000u);
}

__global__ __launch_bounds__(256)
void gather_slice4_kernel(GProb g0, GProb g1) {
    int s = blockIdx.x & 7;
    int chunk = blockIdx.x >> 3;
    int grp = threadIdx.x >> 2;     // 0..63: row within chunk
    int c   = threadIdx.x & 3;      // lane-in-group: cols 4c..4c+3
    const bool firstp = (chunk < GCH64);
    const GProb& g = firstp ? g0 : g1;
    int row = (firstp ? chunk : chunk - GCH64) * 64 + grp;
    if (row >= g.N) return;
    int beg = g.offs[row], end = g.offs[row + 1];
    const upk4* __restrict__ base =
        reinterpret_cast<const upk4*>(g.Hp + ((size_t)s * NUSER) * 16) + c;
    float4 a = make_float4(0.f, 0.f, 0.f, 0.f);
    int e = beg;
    for (; e + 3 < end; e += 4) {
        int r0 = __builtin_nontemporal_load(&g.bkt[e]);
        int r1 = __builtin_nontemporal_load(&g.bkt[e + 1]);
        int r2 = __builtin_nontemporal_load(&g.bkt[e + 2]);
        int r3 = __builtin_nontemporal_load(&g.bkt[e + 3]);
        upk4 v0 = base[(size_t)r0 * 4];
        upk4 v1 = base[(size_t)r1 * 4];
        upk4 v2 = base[(size_t)r2 * 4];
        upk4 v3 = base[(size_t)r3 * 4];
        gacc(a, v0); gacc(a, v1); gacc(a, v2); gacc(a, v3);
    }
    for (; e < end; ++e) {
        int r0 = __builtin_nontemporal_load(&g.bkt[e]);
        gacc(a, base[(size_t)r0 * 4]);
    }
    float d = (float)max(end - beg, 1);
    upk4 o;
    o.x = pack_hl(a.x / d); o.y = pack_hl(a.y / d);
    o.z = pack_hl(a.z / d); o.w = pack_hl(a.w / d);
    __builtin_nontemporal_store(o,
        reinterpret_cast<upk4*>(g.Op + ((size_t)s * NUSER + row) * 16) + c);
}

// ---------------------------------------------------------------------------
extern "C" void kernel_launch(void* const* d_in, const int* in_sizes, int n_in,
                              void* d_out, int out_size, void* d_ws, size_t ws_size,
                              hipStream_t stream) {
    const float* x_user  = (const float*)d_in[0];
    const float* x_item  = (const float*)d_in[1];
    const int*   t_user  = (const int*)d_in[2];
    const int*   t_item  = (const int*)d_in[3];
    const int*   eui_src = (const int*)d_in[4];
    const int*   eui_dst = (const int*)d_in[5];
    const int*   eiu_src = (const int*)d_in[6];
    const int*   eiu_dst = (const int*)d_in[7];
    const float* te_W1 = (const float*)d_in[8];  const float* te_b1 = (const float*)d_in[9];
    const float* te_W2 = (const float*)d_in[10]; const float* te_b2 = (const float*)d_in[11];
    const float* proj_Wu = (const float*)d_in[12]; const float* proj_bu = (const float*)d_in[13];
    const float* proj_Wi = (const float*)d_in[14]; const float* proj_bi = (const float*)d_in[15];
    const float* sage_Wnbr  = (const float*)d_in[16];
    const float* sage_Wroot = (const float*)d_in[17];
    const float* sage_b     = (const float*)d_in[18];
    const float* mu_W1 = (const float*)d_in[19]; const float* mu_b1 = (const float*)d_in[20];
    const float* mu_W2 = (const float*)d_in[21]; const float* mu_b2 = (const float*)d_in[22];
    const float* mu_W3 = (const float*)d_in[23]; const float* mu_b3 = (const float*)d_in[24];
    const float* mi_W1 = (const float*)d_in[25]; const float* mi_b1 = (const float*)d_in[26];
    const float* mi_W2 = (const float*)d_in[27]; const float* mi_b2 = (const float*)d_in[28];
    const float* mi_W3 = (const float*)d_in[29]; const float* mi_b3 = (const float*)d_in[30];

    float* out_u = (float*)d_out;                  // [25000][64]
    float* out_i = out_u + (size_t)NIN * 64;       // [25000][32]

    // ---- workspace layout (packed uint planes, slice-major) ----
    const size_t PL = (size_t)NUSER * DIMT;        // 6.4M elems
    float* Tlut = (float*)d_ws;                    // 1000*128 fp32
    unsigned* up = (unsigned*)(Tlut + NTVAL * 128);
    unsigned* Hp_u = up;
    unsigned* Hp_i = up + PL;
    unsigned* G0   = up + 2 * PL;
    unsigned* G1   = up + 3 * PL;
    ushort_t* WT   = (ushort_t*)(up + 4 * PL);

    WDescs wd;
    unsigned woff[16];
    unsigned off = 0; int wi = 0;
    auto addw = [&](const float* src, int K, int N) {
        wd.d[wi].src = src; wd.d[wi].K = K; wd.d[wi].N = N; wd.d[wi].dst = off;
        woff[wi] = off; off += 2u * K * N; ++wi;
    };
    addw(proj_Wu, 64, 128);                                    // 0
    addw(proj_Wi, 32, 128);                                    // 1
    for (int l = 0; l < 2; ++l)
        for (int e = 0; e < 2; ++e)
            addw(sage_Wnbr + (size_t)(l * 2 + e) * DIMT * DIMT, 128, 128);   // 2..5
    for (int l = 0; l < 2; ++l)
        for (int e = 0; e < 2; ++e)
            addw(sage_Wroot + (size_t)(l * 2 + e) * DIMT * DIMT, 128, 128);  // 6..9
    addw(mu_W1, 128, 256);                                     // 10
    addw(mu_W2, 256, 256);                                     // 11
    addw(mu_W3, 256, 64);                                      // 12
    addw(mi_W1, 128, 256);                                     // 13
    addw(mi_W2, 256, 256);                                     // 14
    addw(mi_W3, 256, 32);                                      // 15

    int* ip = (int*)(WT + off + (off & 1));
    int* cnt2   = ip;  ip += 2 * NUSER;            // memset'd
    int* wp2    = ip;  ip += 2 * NUSER;
    int* off_ui = ip;  ip += NUSER + 1;
    int* off_iu = ip;  ip += NUSER + 1;
    int* bsum2  = ip;  ip += 64;
    unsigned* pe0 = (unsigned*)ip;  ip += NEDGE;
    unsigned* pe1 = (unsigned*)ip;  ip += NEDGE;
    ushort_t* bkt_ui = (ushort_t*)ip;
    ushort_t* bkt_iu = bkt_ui + NEDGE;

    MProb qn = {}; qn.nblk = 0;

    // x packed planes live in the G region until proj is done
    unsigned* xu_p = G0;
    unsigned* xi_p = G1;

    // ---- prep ----
    hipMemsetAsync(cnt2, 0, 2 * NUSER * sizeof(int), stream);
    prep_kernel<<<PREP_LUT + PREP_CVTW + PREP_CVTX + PREP_HIST, 256, 0, stream>>>(
        wd, WT, te_W1, te_b1, te_W2, te_b2, Tlut,
        x_user, x_item, xu_p, xi_p,
        eui_src, eui_dst, eiu_src, eiu_dst, pe0, pe1, cnt2);

    // ---- CSR build ----
    scan1x2_kernel<<<2 * GSCAN, 256, 0, stream>>>(cnt2, bsum2);
    scan3x2_kernel<<<2 * GSCAN, 256, 0, stream>>>(cnt2, bsum2, off_ui, off_iu, wp2);
    fill2p_kernel<<<8 * FILL_CH, 256, 0, stream>>>(pe0, pe1, wp2, bkt_ui, bkt_iu);

    // ---- proj: h = x@W + b + Tlut[t] ----
    {
        MProb qu = {}; MProb qi = {};
        qu.A1p = xu_p; qu.K1 = 64;
        qu.W1 = WT + woff[0]; qu.bias = proj_bu; qu.res = Tlut; qu.tidx = t_user;
        qu.Yp = Hp_u; qu.M = NUSER; qu.nblk = (NUSER + 127) / 128;
        qu.anr = NUSER; qu.ynr = NUSER;
        qi.A1p = xi_p; qi.K1 = 32;
        qi.W1 = WT + woff[1]; qi.bias = proj_bi; qi.res = Tlut; qi.tidx = t_item;
        qi.Yp = Hp_i; qi.M = NITEM; qi.nblk = (NITEM + 127) / 128;
        qi.anr = NITEM; qi.ynr = NITEM;
        mgemm_kernel<128, ACT_NONE, false, 2, 2><<<qu.nblk + qi.nblk, 256, 0, stream>>>(qu, qi);
    }

    // ---- SAGE layers: slice gather, paired dual GEMM ----
    for (int l = 0; l < 2; ++l) {
        {
            GProb gi = { Hp_u, off_ui, bkt_ui, G0, NITEM };
            GProb gu = { Hp_i, off_iu, bkt_iu, G1, NUSER };
            gather_slice4_kernel<<<8 * 2 * GCH64, 256, 0, stream>>>(gi, gu);
        }
        {
            MProb qi = {}; MProb qu = {};
            qi.A1p = G0; qi.K1 = 128;
            qi.A2p = Hp_i; qi.K2 = 128;
            qi.W1 = WT + woff[2 + l * 2 + 0]; qi.W2 = WT + woff[6 + l * 2 + 0];
            qi.bias = sage_b + (size_t)(l * 2 + 0) * DIMT;
            qi.Yp = Hp_i; qi.M = NITEM; qi.nblk = (NITEM + 127) / 128;
            qi.anr = NUSER; qi.ynr = NUSER;
            qu.A1p = G1; qu.K1 = 128;
            qu.A2p = Hp_u; qu.K2 = 128;
            qu.W1 = WT + woff[2 + l * 2 + 1]; qu.W2 = WT + woff[6 + l * 2 + 1];
            qu.bias = sage_b + (size_t)(l * 2 + 1) * DIMT;
            qu.Yp = Hp_u; qu.M = NUSER; qu.nblk = (NUSER + 127) / 128;
            qu.anr = NUSER; qu.ynr = NUSER;
            mgemm_kernel<128, ACT_RELU, true, 0, 2><<<qi.nblk + qu.nblk, 256, 0, stream>>>(qi, qu);
        }
    }

    // ---- MLP heads (rows 0..25000) ----
    unsigned* Tp_u = G0;
    unsigned* Tp_i = G1;
    {
        MProb qu = {}; MProb qi = {};
        qu.A1p = Hp_u; qu.K1 = 128;
        qu.W1 = WT + woff[10]; qu.bias = mu_b1;
        qu.Yp = Tp_u; qu.M = NIN; qu.nblk = (NIN + 63) / 64;
        qu.anr = NUSER; qu.ynr = NIN;
        qi.A1p = Hp_i; qi.K1 = 128;
        qi.W1 = WT + woff[13]; qi.bias = mi_b1;
        qi.Yp = Tp_i; qi.M = NIN; qi.nblk = (NIN + 63) / 64;
        qi.anr = NUSER; qi.ynr = NIN;
        mgemm_kernel<256, ACT_RELU, false, 0, 2><<<qu.nblk + qi.nblk, 256, 0, stream>>>(qu, qi);
    }
    {
        MProb qu = {}; MProb qi = {};
        qu.A1p = Tp_u; qu.K1 = 256;
        qu.W1 = WT + woff[11]; qu.bias = mu_b2;
        qu.Yp = Tp_u; qu.M = NIN; qu.nblk = (NIN + 63) / 64;   // in-place (block-local rows)
        qu.anr = NIN; qu.ynr = NIN;
        qi.A1p = Tp_i; qi.K1 = 256;
        qi.W1 = WT + woff[14]; qi.bias = mi_b2;
        qi.Yp = Tp_i; qi.M = NIN; qi.nblk = (NIN + 63) / 64;
        qi.anr = NIN; qi.ynr = NIN;
        mgemm_kernel<256, ACT_RELU, false, 0, 2><<<qu.nblk + qi.nblk, 256, 0, stream>>>(qu, qi);
    }
    {
        MProb q = {};
        q.A1p = Tp_u; q.K1 = 256;
        q.W1 = WT + woff[12]; q.bias = mu_b3;
        q.Yf = out_u; q.M = NIN; q.nblk = (NIN + 255) / 256;
        q.anr = NIN; q.ynr = NIN;
        mgemm_kernel<64, ACT_NONE, false, 0, 1><<<q.nblk, 256, 0, stream>>>(q, qn);
    }
    {
        MProb q = {};
        q.A1p = Tp_i; q.K1 = 256;
        q.W1 = WT + woff[15]; q.bias = mi_b3;
        q.Yf = out_i; q.M = NIN; q.nblk = (NIN + 255) / 256;
        q.anr = NIN; q.ynr = NIN;
        mgemm_kernel<32, ACT_NONE, false, 0, 1><<<q.nblk, 256, 0, stream>>>(q, qn);
    }

    (void)in_sizes; (void)n_in; (void)out_size; (void)ws_size;
}

// Round 18
// 497.504 us; speedup vs baseline: 1.2007x; 1.2007x over previous
//
#include <hip/hip_runtime.h>
#include <math.h>

#define NEDGE 600000
#define NUSER 50000
#define NITEM 50000
#define DIMT  128
#define NIN   25000
#define NTVAL 1000

typedef unsigned short ushort_t;
typedef __attribute__((ext_vector_type(8))) short bf16x8;
typedef __attribute__((ext_vector_type(8))) unsigned short us8;
typedef __attribute__((ext_vector_type(4))) float f32x4;
typedef __attribute__((ext_vector_type(4))) unsigned upk4;

// packed element: low16 = hi bf16, high16 = lo bf16 ; value = fh + fl
__device__ __forceinline__ unsigned pack_hl(float f) {
    unsigned u = __float_as_uint(f);
    unsigned r = u + 0x7fffu + ((u >> 16) & 1u);
    unsigned h = (r >> 16) & 0xffffu;
    float fh = __uint_as_float(h << 16);
    float fl = f - fh;
    unsigned ul = __float_as_uint(fl);
    unsigned rl = ul + 0x7fffu + ((ul >> 16) & 1u);
    return h | (rl & 0xffff0000u);
}
__device__ __forceinline__ void split_bf16(float f, ushort_t& h, ushort_t& l) {
    unsigned p = pack_hl(f);
    h = (ushort_t)(p & 0xffffu);
    l = (ushort_t)(p >> 16);
}

// deinterleave 8 packed uints -> bf16x8 hi, bf16x8 lo
__device__ __forceinline__ void unpack_frag(upk4 p0, upk4 p1, bf16x8& ah, bf16x8& al) {
    upk4 h, l;
#if __has_builtin(__builtin_amdgcn_perm)
    h.x = __builtin_amdgcn_perm(p0.y, p0.x, 0x05040100u);
    h.y = __builtin_amdgcn_perm(p0.w, p0.z, 0x05040100u);
    h.z = __builtin_amdgcn_perm(p1.y, p1.x, 0x05040100u);
    h.w = __builtin_amdgcn_perm(p1.w, p1.z, 0x05040100u);
    l.x = __builtin_amdgcn_perm(p0.y, p0.x, 0x07060302u);
    l.y = __builtin_amdgcn_perm(p0.w, p0.z, 0x07060302u);
    l.z = __builtin_amdgcn_perm(p1.y, p1.x, 0x07060302u);
    l.w = __builtin_amdgcn_perm(p1.w, p1.z, 0x07060302u);
#else
    h.x = (p0.x & 0xffffu) | (p0.y << 16);
    h.y = (p0.z & 0xffffu) | (p0.w << 16);
    h.z = (p1.x & 0xffffu) | (p1.y << 16);
    h.w = (p1.z & 0xffffu) | (p1.w << 16);
    l.x = (p0.x >> 16) | (p0.y & 0xffff0000u);
    l.y = (p0.z >> 16) | (p0.w & 0xffff0000u);
    l.z = (p1.x >> 16) | (p1.y & 0xffff0000u);
    l.w = (p1.z >> 16) | (p1.w & 0xffff0000u);
#endif
    ah = __builtin_bit_cast(bf16x8, h);
    al = __builtin_bit_cast(bf16x8, l);
}

// slice-major plane addressing: elem (row,k) at ((k>>4)*nr + row)*16 + (k&15)
__device__ __forceinline__ size_t sm_addr(int row, int k, int nr) {
    return ((size_t)(k >> 4) * (unsigned)nr + (unsigned)row) * 16 + (k & 15);
}

// ---------------------------------------------------------------------------
// prep: LUT (4-way ILP) | weight cvt (write-contiguous) | x cvt + edge pack |
//       XCD-partitioned histogram
// ---------------------------------------------------------------------------
struct WDesc { const float* src; int K; int N; unsigned dst; };
struct WDescs { WDesc d[16]; };

#define PREP_LUT  500
#define PREP_CVTW 256
#define PREP_CVTX 512
#define HIST_CH   256
#define PREP_HIST (8 * HIST_CH)
#define DRANGE    (NUSER / 8)

__global__ __launch_bounds__(256) void prep_kernel(
        WDescs wd, ushort_t* __restrict__ WT,
        const float* __restrict__ teW1, const float* __restrict__ teb1,
        const float* __restrict__ teW2, const float* __restrict__ teb2,
        float* __restrict__ Tlut,
        const float* __restrict__ xu, const float* __restrict__ xi,
        unsigned* __restrict__ xup, unsigned* __restrict__ xip,
        const int* __restrict__ s0, const int* __restrict__ d0,
        const int* __restrict__ s1, const int* __restrict__ d1,
        unsigned* __restrict__ pe0, unsigned* __restrict__ pe1,
        int* __restrict__ cnt2) {
    __shared__ float sE[2][128];
    __shared__ float sH[2][128];
    int b = blockIdx.x;
    int tid = threadIdx.x;
    if (b < PREP_LUT) {
        int r = tid >> 7, j = tid & 127;
        int t = b * 2 + r;
        {
            int jj = j & 63;
            const float Lf = 9.210340371976184f;
            float p  = -Lf * (float)jj;
            float ae = p * 0.015625f;
            float freq = (float)exp((double)ae);
            float arg  = (float)t * freq;
            double a = (double)arg;
            sE[r][j] = (j < 64) ? (float)cos(a) : (float)sin(a);
        }
        __syncthreads();
        {
            float a0 = 0.f, a1 = 0.f, a2 = 0.f, a3 = 0.f;
            for (int k = 0; k < 128; k += 4) {
                a0 = fmaf(sE[r][k],     teW1[(k)     * 128 + j], a0);
                a1 = fmaf(sE[r][k + 1], teW1[(k + 1) * 128 + j], a1);
                a2 = fmaf(sE[r][k + 2], teW1[(k + 2) * 128 + j], a2);
                a3 = fmaf(sE[r][k + 3], teW1[(k + 3) * 128 + j], a3);
            }
            float acc = teb1[j] + ((a0 + a1) + (a2 + a3));
            float s = 1.f / (1.f + expf(-acc));
            sH[r][j] = acc * s;
        }
        __syncthreads();
        {
            float a0 = 0.f, a1 = 0.f, a2 = 0.f, a3 = 0.f;
            for (int k = 0; k < 128; k += 4) {
                a0 = fmaf(sH[r][k],     teW2[(k)     * 128 + j], a0);
                a1 = fmaf(sH[r][k + 1], teW2[(k + 1) * 128 + j], a1);
                a2 = fmaf(sH[r][k + 2], teW2[(k + 2) * 128 + j], a2);
                a3 = fmaf(sH[r][k + 3], teW2[(k + 3) * 128 + j], a3);
            }
            Tlut[(size_t)t * 128 + j] = teb2[j] + ((a0 + a1) + (a2 + a3));
        }
    } else if (b < PREP_LUT + PREP_CVTW) {
        int g = (b - PREP_LUT) * 256 + tid;
        int gs = PREP_CVTW * 256;
#pragma unroll 1
        for (int i = 0; i < 16; ++i) {
            const WDesc w = wd.d[i];
            int sz = w.K * w.N;
            int ng = sz >> 3;                 // groups of 8 contiguous outputs
            int kshift = 31 - __clz(w.K);     // K is a power of two
            int kmask = w.K - 1;
            ushort_t* ph = WT + w.dst;
            ushort_t* pl = ph + sz;
            for (int t = g; t < ng; t += gs) {
                int e8 = t << 3;              // output index: n*K + k0
                int n  = e8 >> kshift;
                int k0 = e8 & kmask;
                us8 hb, lb;
#pragma unroll
                for (int j = 0; j < 8; ++j) {
                    ushort_t h, l;
                    split_bf16(w.src[(size_t)(k0 + j) * w.N + n], h, l);
                    hb[j] = h; lb[j] = l;
                }
                *reinterpret_cast<us8*>(ph + e8) = hb;   // 16B contiguous stores
                *reinterpret_cast<us8*>(pl + e8) = lb;
            }
        }
    } else if (b < PREP_LUT + PREP_CVTW + PREP_CVTX) {
        int g = (b - PREP_LUT - PREP_CVTW) * 256 + tid;
        int gs = PREP_CVTX * 256;
        for (int i = g; i < NUSER * 64; i += gs) {
            int row = i >> 6, k = i & 63;
            xup[sm_addr(row, k, NUSER)] = pack_hl(xu[i]);
        }
        for (int i = g; i < NITEM * 32; i += gs) {
            int row = i >> 5, k = i & 31;
            xip[sm_addr(row, k, NITEM)] = pack_hl(xi[i]);
        }
        for (int i = g; i < NEDGE; i += gs) {
            pe0[i] = ((unsigned)d0[i] & 0xffffu) | ((unsigned)s0[i] << 16);
            pe1[i] = ((unsigned)d1[i] & 0xffffu) | ((unsigned)s1[i] << 16);
        }
    } else {
        // XCD-range-partitioned histogram
        int hb = b - PREP_LUT - PREP_CVTW - PREP_CVTX;
        int r = hb & 7, c = hb >> 3;
        int lo = r * DRANGE, hi = lo + DRANGE;
        const int epb = (NEDGE + HIST_CH - 1) / HIST_CH;
        int e0 = c * epb, e1 = min(e0 + epb, NEDGE);
        for (int e = e0 + tid; e < e1; e += 256) {
            int d = d0[e];
            if (d >= lo && d < hi) atomicAdd(&cnt2[d], 1);
        }
        for (int e = e0 + tid; e < e1; e += 256) {
            int d = d1[e];
            if (d >= lo && d < hi) atomicAdd(&cnt2[NUSER + d], 1);
        }
    }
}

// ---------------------------------------------------------------------------
// MFMA GEMM (split-bf16, 3-pass):  Y = act( A@W1 [+ A2@W2] + bias [+ res] )
// A: packed uint planes, SLICE-MAJOR (stride anr). W: transposed hi/lo.
// OUTMODE bit0: fp32 row-major Yf; bit1: slice-major packed Yp (stride ynr).
// ---------------------------------------------------------------------------
#define ACT_NONE 0
#define ACT_RELU 1

struct MProb {
    const unsigned *A1p; int K1;
    const unsigned *A2p; int K2;
    const ushort_t *W1, *W2;            // hi plane; lo at +NOUT*K
    const float* bias; const float* res; const int* tidx;
    float* Yf; unsigned* Yp;
    int M; int nblk; int anr; int ynr;
};

template<int NOUT, int ACT, bool DUAL, int RESMODE, int OUTMODE>
__global__ __launch_bounds__(256)
void mgemm_kernel(MProb q0, MProb q1) {
    constexpr int WN  = (NOUT >= 64) ? 64 : NOUT;
    constexpr int NWC = NOUT / WN;
    constexpr int NWR = 4 / NWC;
    constexpr int BM  = NWR * 64;
    constexpr int NF  = WN / 16;

    const bool firstp = (blockIdx.x < (unsigned)q0.nblk);
    const MProb& q = firstp ? q0 : q1;
    const int bid = firstp ? blockIdx.x : (blockIdx.x - q0.nblk);

    const int w    = threadIdx.x >> 6;
    const int lane = threadIdx.x & 63;
    const int wc   = w % NWC;
    const int wr   = w / NWC;
    const int mw   = bid * BM + wr * 64;
    const int nw   = wc * WN;
    const int lr   = lane & 15;
    const int lkg  = lane >> 4;

    f32x4 acc[4][NF];
#pragma unroll
    for (int i = 0; i < 4; ++i)
#pragma unroll
        for (int j = 0; j < NF; ++j) acc[i][j] = (f32x4)0.f;

    const int nkt1 = q.K1 / 32;
    const int nkt  = nkt1 + (DUAL ? q.K2 / 32 : 0);

    upk4 pa[4][2];
    auto loadA = [&](int kt) {
        const unsigned* Ap; int kk;
        if (!DUAL || kt < nkt1) { Ap = q.A1p; kk = kt * 32; }
        else                    { Ap = q.A2p; kk = (kt - nkt1) * 32; }
        const int kb = kk + lkg * 8;          // kb % 16 in {0,8}
#pragma unroll
        for (int mf = 0; mf < 4; ++mf) {
            int row = mw + mf * 16 + lr;
            if (row < q.M) {
                const upk4* p = reinterpret_cast<const upk4*>(Ap + sm_addr(row, kb, q.anr));
                pa[mf][0] = p[0]; pa[mf][1] = p[1];
            } else {
                pa[mf][0] = (upk4)0u; pa[mf][1] = (upk4)0u;
            }
        }
    };

    loadA(0);
#pragma unroll 1
    for (int kt = 0; kt < nkt; ++kt) {
        bf16x8 a_h[4], a_l[4];
#pragma unroll
        for (int mf = 0; mf < 4; ++mf) unpack_frag(pa[mf][0], pa[mf][1], a_h[mf], a_l[mf]);
        if (kt + 1 < nkt) loadA(kt + 1);          // prefetch next A tile

        const ushort_t* Wh; int K, kk;
        if (!DUAL || kt < nkt1) { Wh = q.W1; K = q.K1; kk = kt * 32; }
        else                    { Wh = q.W2; K = q.K2; kk = (kt - nkt1) * 32; }
        const ushort_t* Wl = Wh + (size_t)NOUT * K;
        const int kb = kk + lkg * 8;
        bf16x8 b_h[NF], b_l[NF];
#pragma unroll
        for (int nf = 0; nf < NF; ++nf) {
            int col = nw + nf * 16 + lr;
            b_h[nf] = *reinterpret_cast<const bf16x8*>(Wh + (size_t)col * K + kb);
            b_l[nf] = *reinterpret_cast<const bf16x8*>(Wl + (size_t)col * K + kb);
        }
#pragma unroll
        for (int mf = 0; mf < 4; ++mf)
#pragma unroll
            for (int nf = 0; nf < NF; ++nf) {
                acc[mf][nf] = __builtin_amdgcn_mfma_f32_16x16x32_bf16(a_h[mf], b_h[nf], acc[mf][nf], 0, 0, 0);
                acc[mf][nf] = __builtin_amdgcn_mfma_f32_16x16x32_bf16(a_h[mf], b_l[nf], acc[mf][nf], 0, 0, 0);
                acc[mf][nf] = __builtin_amdgcn_mfma_f32_16x16x32_bf16(a_l[mf], b_h[nf], acc[mf][nf], 0, 0, 0);
            }
    }

    // all reads complete before in-place epilogue stores (waves share rows)
    __syncthreads();

    float bcol[NF];
#pragma unroll
    for (int nf = 0; nf < NF; ++nf) bcol[nf] = q.bias[nw + nf * 16 + lr];

#pragma unroll
    for (int mf = 0; mf < 4; ++mf) {
#pragma unroll
        for (int r = 0; r < 4; ++r) {
            int row = mw + mf * 16 + lkg * 4 + r;
            if (row >= q.M) continue;
            const float* rp = nullptr;
            if (RESMODE == 2) { int tv = q.tidx[row]; rp = q.res + (size_t)tv * NOUT; }
#pragma unroll
            for (int nf = 0; nf < NF; ++nf) {
                int col = nw + nf * 16 + lr;
                float v = acc[mf][nf][r] + bcol[nf];
                if (RESMODE == 2) v += rp[col];
                if (ACT == ACT_RELU) v = fmaxf(v, 0.f);
                if (OUTMODE & 1) q.Yf[(size_t)row * NOUT + col] = v;
                if (OUTMODE & 2) q.Yp[sm_addr(row, col, q.ynr)] = pack_hl(v);
            }
        }
    }
}

// ---------------------------------------------------------------------------
// CSR scans
// ---------------------------------------------------------------------------
#define SCAN_CHUNK 2048
#define GSCAN 25

__global__ __launch_bounds__(256) void scan1x2_kernel(const int* __restrict__ cnt2,
                                                      int* __restrict__ bsum2) {
    __shared__ int sdata[256];
    int p = blockIdx.x / GSCAN, b = blockIdx.x % GSCAN;
    const int* cnt = cnt2 + p * NUSER;
    int base = b * SCAN_CHUNK + threadIdx.x * 8;
    int s = 0;
#pragma unroll
    for (int j = 0; j < 8; ++j) { int i = base + j; if (i < NUSER) s += cnt[i]; }
    sdata[threadIdx.x] = s;
    __syncthreads();
    for (int st = 128; st > 0; st >>= 1) {
        if ((int)threadIdx.x < st) sdata[threadIdx.x] += sdata[threadIdx.x + st];
        __syncthreads();
    }
    if (threadIdx.x == 0) bsum2[p * 32 + b] = sdata[0];
}

__global__ __launch_bounds__(256) void scan3x2_kernel(const int* __restrict__ cnt2,
                                                      const int* __restrict__ bsum2,
                                                      int* __restrict__ off_ui,
                                                      int* __restrict__ off_iu,
                                                      int* __restrict__ wp2) {
    __shared__ int sth[256];
    int p = blockIdx.x / GSCAN, b = blockIdx.x % GSCAN;
    const int* cnt = cnt2 + p * NUSER;
    int* offs = p ? off_iu : off_ui;
    int* wp = wp2 + p * NUSER;
    int t = threadIdx.x;
    int boff = 0;
    for (int i = 0; i < b; ++i) boff += bsum2[p * 32 + i];
    int base = b * SCAN_CHUNK + t * 8;
    int loc[8];
    int s = 0;
#pragma unroll
    for (int j = 0; j < 8; ++j) {
        int i = base + j;
        int v = (i < NUSER) ? cnt[i] : 0;
        loc[j] = s; s += v;
    }
    sth[t] = s;
    __syncthreads();
    for (int st = 1; st < 256; st <<= 1) {
        int v = (t >= st) ? sth[t - st] : 0;
        __syncthreads();
        sth[t] += v;
        __syncthreads();
    }
    int exc = (t == 0) ? 0 : sth[t - 1];
#pragma unroll
    for (int j = 0; j < 8; ++j) {
        int i = base + j;
        if (i < NUSER) { int o = boff + exc + loc[j]; offs[i] = o; wp[i] = o; }
    }
    if (b == GSCAN - 1 && t == 255) offs[NUSER] = boff + sth[255];
}

// ---------------------------------------------------------------------------
// XCD-partitioned bucket fill from packed edges (dst|src<<16)
// ---------------------------------------------------------------------------
#define FILL_CH 256

__global__ __launch_bounds__(256) void fill2p_kernel(
        const unsigned* __restrict__ pe0, const unsigned* __restrict__ pe1,
        int* __restrict__ wp2,
        ushort_t* __restrict__ bkt0, ushort_t* __restrict__ bkt1) {
    int r = blockIdx.x & 7, c = blockIdx.x >> 3;
    int lo = r * DRANGE, hi = lo + DRANGE;
    const int epb = (NEDGE + FILL_CH - 1) / FILL_CH;
    int e0 = c * epb, e1 = min(e0 + epb, NEDGE);
#pragma unroll 4
    for (int e = e0 + (int)threadIdx.x; e < e1; e += 256) {
        unsigned p = pe0[e];
        int d = (int)(p & 0xffffu);
        if (d >= lo && d < hi) { int pos = atomicAdd(&wp2[d], 1); bkt0[pos] = (ushort_t)(p >> 16); }
    }
#pragma unroll 4
    for (int e = e0 + (int)threadIdx.x; e < e1; e += 256) {
        unsigned p = pe1[e];
        int d = (int)(p & 0xffffu);
        if (d >= lo && d < hi) { int pos = atomicAdd(&wp2[NUSER + d], 1); bkt1[pos] = (ushort_t)(p >> 16); }
    }
}

// ---------------------------------------------------------------------------
// Slice-partitioned segment-mean, 4-lane groups, natural row order,
// 4-edge ILP + float4 accumulator. Block s=blockIdx&7 reads only slice s
// (3.2MB, XCD-L2-resident).
// ---------------------------------------------------------------------------
struct GProb { const unsigned* Hp; const int* offs; const ushort_t* bkt;
               unsigned* Op; int N; };
#define GCH64 782   // ceil(50000/64)

__device__ __forceinline__ void gacc(float4& a, upk4 v) {
    a.x += __uint_as_float(v.x << 16);
    a.y += __uint_as_float(v.y << 16);
    a.z += __uint_as_float(v.z << 16);
    a.w += __uint_as_float(v.w << 16);
    a.x += __uint_as_float(v.x & 0xffff0000u);
    a.y += __uint_as_float(v.y & 0xffff0000u);
    a.z += __uint_as_float(v.z & 0xffff0000u);
    a.w += __uint_as_float(v.w & 0xffff0000u);
}

__global__ __launch_bounds__(256)
void gather_slice4_kernel(GProb g0, GProb g1) {
    int s = blockIdx.x & 7;
    int chunk = blockIdx.x >> 3;
    int grp = threadIdx.x >> 2;     // 0..63: row within chunk
    int c   = threadIdx.x & 3;      // lane-in-group: cols 4c..4c+3
    const bool firstp = (chunk < GCH64);
    const GProb& g = firstp ? g0 : g1;
    int row = (firstp ? chunk : chunk - GCH64) * 64 + grp;
    if (row >= g.N) return;
    int beg = g.offs[row], end = g.offs[row + 1];
    const upk4* __restrict__ base =
        reinterpret_cast<const upk4*>(g.Hp + ((size_t)s * NUSER) * 16) + c;
    float4 a = make_float4(0.f, 0.f, 0.f, 0.f);
    int e = beg;
    for (; e + 3 < end; e += 4) {
        int r0 = g.bkt[e], r1 = g.bkt[e + 1], r2 = g.bkt[e + 2], r3 = g.bkt[e + 3];
        upk4 v0 = base[(size_t)r0 * 4];
        upk4 v1 = base[(size_t)r1 * 4];
        upk4 v2 = base[(size_t)r2 * 4];
        upk4 v3 = base[(size_t)r3 * 4];
        gacc(a, v0); gacc(a, v1); gacc(a, v2); gacc(a, v3);
    }
    for (; e < end; ++e) gacc(a, base[(size_t)g.bkt[e] * 4]);
    float d = (float)max(end - beg, 1);
    upk4 o;
    o.x = pack_hl(a.x / d); o.y = pack_hl(a.y / d);
    o.z = pack_hl(a.z / d); o.w = pack_hl(a.w / d);
    *(reinterpret_cast<upk4*>(g.Op + ((size_t)s * NUSER + row) * 16) + c) = o;
}

// ---------------------------------------------------------------------------
extern "C" void kernel_launch(void* const* d_in, const int* in_sizes, int n_in,
                              void* d_out, int out_size, void* d_ws, size_t ws_size,
                              hipStream_t stream) {
    const float* x_user  = (const float*)d_in[0];
    const float* x_item  = (const float*)d_in[1];
    const int*   t_user  = (const int*)d_in[2];
    const int*   t_item  = (const int*)d_in[3];
    const int*   eui_src = (const int*)d_in[4];
    const int*   eui_dst = (const int*)d_in[5];
    const int*   eiu_src = (const int*)d_in[6];
    const int*   eiu_dst = (const int*)d_in[7];
    const float* te_W1 = (const float*)d_in[8];  const float* te_b1 = (const float*)d_in[9];
    const float* te_W2 = (const float*)d_in[10]; const float* te_b2 = (const float*)d_in[11];
    const float* proj_Wu = (const float*)d_in[12]; const float* proj_bu = (const float*)d_in[13];
    const float* proj_Wi = (const float*)d_in[14]; const float* proj_bi = (const float*)d_in[15];
    const float* sage_Wnbr  = (const float*)d_in[16];
    const float* sage_Wroot = (const float*)d_in[17];
    const float* sage_b     = (const float*)d_in[18];
    const float* mu_W1 = (const float*)d_in[19]; const float* mu_b1 = (const float*)d_in[20];
    const float* mu_W2 = (const float*)d_in[21]; const float* mu_b2 = (const float*)d_in[22];
    const float* mu_W3 = (const float*)d_in[23]; const float* mu_b3 = (const float*)d_in[24];
    const float* mi_W1 = (const float*)d_in[25]; const float* mi_b1 = (const float*)d_in[26];
    const float* mi_W2 = (const float*)d_in[27]; const float* mi_b2 = (const float*)d_in[28];
    const float* mi_W3 = (const float*)d_in[29]; const float* mi_b3 = (const float*)d_in[30];

    float* out_u = (float*)d_out;                  // [25000][64]
    float* out_i = out_u + (size_t)NIN * 64;       // [25000][32]

    // ---- workspace layout (packed uint planes, slice-major) ----
    const size_t PL = (size_t)NUSER * DIMT;        // 6.4M elems
    float* Tlut = (float*)d_ws;                    // 1000*128 fp32
    unsigned* up = (unsigned*)(Tlut + NTVAL * 128);
    unsigned* Hp_u = up;
    unsigned* Hp_i = up + PL;
    unsigned* G0   = up + 2 * PL;
    unsigned* G1   = up + 3 * PL;
    ushort_t* WT   = (ushort_t*)(up + 4 * PL);

    WDescs wd;
    unsigned woff[16];
    unsigned off = 0; int wi = 0;
    auto addw = [&](const float* src, int K, int N) {
        wd.d[wi].src = src; wd.d[wi].K = K; wd.d[wi].N = N; wd.d[wi].dst = off;
        woff[wi] = off; off += 2u * K * N; ++wi;
    };
    addw(proj_Wu, 64, 128);                                    // 0
    addw(proj_Wi, 32, 128);                                    // 1
    for (int l = 0; l < 2; ++l)
        for (int e = 0; e < 2; ++e)
            addw(sage_Wnbr + (size_t)(l * 2 + e) * DIMT * DIMT, 128, 128);   // 2..5
    for (int l = 0; l < 2; ++l)
        for (int e = 0; e < 2; ++e)
            addw(sage_Wroot + (size_t)(l * 2 + e) * DIMT * DIMT, 128, 128);  // 6..9
    addw(mu_W1, 128, 256);                                     // 10
    addw(mu_W2, 256, 256);                                     // 11
    addw(mu_W3, 256, 64);                                      // 12
    addw(mi_W1, 128, 256);                                     // 13
    addw(mi_W2, 256, 256);                                     // 14
    addw(mi_W3, 256, 32);                                      // 15

    int* ip = (int*)(WT + off + (off & 1));
    int* cnt2   = ip;  ip += 2 * NUSER;            // memset'd
    int* wp2    = ip;  ip += 2 * NUSER;
    int* off_ui = ip;  ip += NUSER + 1;
    int* off_iu = ip;  ip += NUSER + 1;
    int* bsum2  = ip;  ip += 64;
    unsigned* pe0 = (unsigned*)ip;  ip += NEDGE;
    unsigned* pe1 = (unsigned*)ip;  ip += NEDGE;
    ushort_t* bkt_ui = (ushort_t*)ip;
    ushort_t* bkt_iu = bkt_ui + NEDGE;

    MProb qn = {}; qn.nblk = 0;

    // x packed planes live in the G region until proj is done
    unsigned* xu_p = G0;
    unsigned* xi_p = G1;

    // ---- prep ----
    hipMemsetAsync(cnt2, 0, 2 * NUSER * sizeof(int), stream);
    prep_kernel<<<PREP_LUT + PREP_CVTW + PREP_CVTX + PREP_HIST, 256, 0, stream>>>(
        wd, WT, te_W1, te_b1, te_W2, te_b2, Tlut,
        x_user, x_item, xu_p, xi_p,
        eui_src, eui_dst, eiu_src, eiu_dst, pe0, pe1, cnt2);

    // ---- CSR build ----
    scan1x2_kernel<<<2 * GSCAN, 256, 0, stream>>>(cnt2, bsum2);
    scan3x2_kernel<<<2 * GSCAN, 256, 0, stream>>>(cnt2, bsum2, off_ui, off_iu, wp2);
    fill2p_kernel<<<8 * FILL_CH, 256, 0, stream>>>(pe0, pe1, wp2, bkt_ui, bkt_iu);

    // ---- proj: h = x@W + b + Tlut[t] ----
    {
        MProb qu = {}; MProb qi = {};
        qu.A1p = xu_p; qu.K1 = 64;
        qu.W1 = WT + woff[0]; qu.bias = proj_bu; qu.res = Tlut; qu.tidx = t_user;
        qu.Yp = Hp_u; qu.M = NUSER; qu.nblk = (NUSER + 127) / 128;
        qu.anr = NUSER; qu.ynr = NUSER;
        qi.A1p = xi_p; qi.K1 = 32;
        qi.W1 = WT + woff[1]; qi.bias = proj_bi; qi.res = Tlut; qi.tidx = t_item;
        qi.Yp = Hp_i; qi.M = NITEM; qi.nblk = (NITEM + 127) / 128;
        qi.anr = NITEM; qi.ynr = NITEM;
        mgemm_kernel<128, ACT_NONE, false, 2, 2><<<qu.nblk + qi.nblk, 256, 0, stream>>>(qu, qi);
    }

    // ---- SAGE layers: slice gather, paired dual GEMM ----
    for (int l = 0; l < 2; ++l) {
        {
            GProb gi = { Hp_u, off_ui, bkt_ui, G0, NITEM };
            GProb gu = { Hp_i, off_iu, bkt_iu, G1, NUSER };
            gather_slice4_kernel<<<8 * 2 * GCH64, 256, 0, stream>>>(gi, gu);
        }
        {
            MProb qi = {}; MProb qu = {};
            qi.A1p = G0; qi.K1 = 128;
            qi.A2p = Hp_i; qi.K2 = 128;
            qi.W1 = WT + woff[2 + l * 2 + 0]; qi.W2 = WT + woff[6 + l * 2 + 0];
            qi.bias = sage_b + (size_t)(l * 2 + 0) * DIMT;
            qi.Yp = Hp_i; qi.M = NITEM; qi.nblk = (NITEM + 127) / 128;
            qi.anr = NUSER; qi.ynr = NUSER;
            qu.A1p = G1; qu.K1 = 128;
            qu.A2p = Hp_u; qu.K2 = 128;
            qu.W1 = WT + woff[2 + l * 2 + 1]; qu.W2 = WT + woff[6 + l * 2 + 1];
            qu.bias = sage_b + (size_t)(l * 2 + 1) * DIMT;
            qu.Yp = Hp_u; qu.M = NUSER; qu.nblk = (NUSER + 127) / 128;
            qu.anr = NUSER; qu.ynr = NUSER;
            mgemm_kernel<128, ACT_RELU, true, 0, 2><<<qi.nblk + qu.nblk, 256, 0, stream>>>(qi, qu);
        }
    }

    // ---- MLP heads (rows 0..25000) ----
    unsigned* Tp_u = G0;
    unsigned* Tp_i = G1;
    {
        MProb qu = {}; MProb qi = {};
        qu.A1p = Hp_u; qu.K1 = 128;
        qu.W1 = WT + woff[10]; qu.bias = mu_b1;
        qu.Yp = Tp_u; qu.M = NIN; qu.nblk = (NIN + 63) / 64;
        qu.anr = NUSER; qu.ynr = NIN;
        qi.A1p = Hp_i; qi.K1 = 128;
        qi.W1 = WT + woff[13]; qi.bias = mi_b1;
        qi.Yp = Tp_i; qi.M = NIN; qi.nblk = (NIN + 63) / 64;
        qi.anr = NUSER; qi.ynr = NIN;
        mgemm_kernel<256, ACT_RELU, false, 0, 2><<<qu.nblk + qi.nblk, 256, 0, stream>>>(qu, qi);
    }
    {
        MProb qu = {}; MProb qi = {};
        qu.A1p = Tp_u; qu.K1 = 256;
        qu.W1 = WT + woff[11]; qu.bias = mu_b2;
        qu.Yp = Tp_u; qu.M = NIN; qu.nblk = (NIN + 63) / 64;   // in-place (block-local rows)
        qu.anr = NIN; qu.ynr = NIN;
        qi.A1p = Tp_i; qi.K1 = 256;
        qi.W1 = WT + woff[14]; qi.bias = mi_b2;
        qi.Yp = Tp_i; qi.M = NIN; qi.nblk = (NIN + 63) / 64;
        qi.anr = NIN; qi.ynr = NIN;
        mgemm_kernel<256, ACT_RELU, false, 0, 2><<<qu.nblk + qi.nblk, 256, 0, stream>>>(qu, qi);
    }
    {
        MProb q = {};
        q.A1p = Tp_u; q.K1 = 256;
        q.W1 = WT + woff[12]; q.bias = mu_b3;
        q.Yf = out_u; q.M = NIN; q.nblk = (NIN + 255) / 256;
        q.anr = NIN; q.ynr = NIN;
        mgemm_kernel<64, ACT_NONE, false, 0, 1><<<q.nblk, 256, 0, stream>>>(q, qn);
    }
    {
        MProb q = {};
        q.A1p = Tp_i; q.K1 = 256;
        q.W1 = WT + woff[15]; q.bias = mi_b3;
        q.Yf = out_i; q.M = NIN; q.nblk = (NIN + 255) / 256;
        q.anr = NIN; q.ynr = NIN;
        mgemm_kernel<32, ACT_NONE, false, 0, 1><<<q.nblk, 256, 0, stream>>>(q, qn);
    }

    (void)in_sizes; (void)n_in; (void)out_size; (void)ws_size;
}